// Round 1
// 1803.712 us; speedup vs baseline: 1.1514x; 1.1514x over previous
//
#include <hip/hip_runtime.h>
#include <cstdint>

#define BN_EPS 1e-5f

typedef __attribute__((ext_vector_type(8))) short bf16x8;
typedef __attribute__((ext_vector_type(4))) float f32x4;

// async 16B global -> LDS (linear: wave-uniform base + lane*16)
#define GLD16(dst, src)                                                        \
  __builtin_amdgcn_global_load_lds(                                            \
      (const __attribute__((address_space(1))) void*)(src),                    \
      (__attribute__((address_space(3))) void*)(dst), 16, 0, 0)

// truncation split: f = hi + lo + O(2^-17 rel); hi/lo exact bf16
__device__ inline void split8(const float* f, bf16x8& hi, bf16x8& lo) {
#pragma unroll
  for (int j = 0; j < 8; ++j) {
    unsigned u = __float_as_uint(f[j]);
    hi[j] = (short)(u >> 16);
    float r = f[j] - __uint_as_float(u & 0xFFFF0000u);
    lo[j] = (short)(__float_as_uint(r) >> 16);
  }
}

// ---------------------------------------------------------------------------
// Tiled fp32 GEMM: C[M x 128] = A[M x K] @ W[128 x K]^T  (kept for K1: px)
// ---------------------------------------------------------------------------
template<int K, bool EPI>
__global__ __launch_bounds__(256) void gemm_kernel(
    const float* __restrict__ A,
    const float* __restrict__ W,      // [128, K] row-major
    const float* __restrict__ bias,   // unused when !EPI
    const float* __restrict__ prelu_a,
    float* __restrict__ C,            // [M, 128]
    float* __restrict__ bnsum,
    float* __restrict__ bnsumsq,
    int M)
{
    constexpr int BM = 64, BN = 128, BK = 32;
    __shared__ float aT[BK][BM + 4];
    __shared__ float wT[BK][BN];

    const int tid = threadIdx.x;
    const int tx = tid & 31;   // col group: cols 4*tx .. 4*tx+3
    const int ty = tid >> 5;   // row group: rows 8*ty .. 8*ty+7
    const int row0 = blockIdx.x * BM;

    float acc[8][4];
#pragma unroll
    for (int r = 0; r < 8; ++r)
#pragma unroll
        for (int c = 0; c < 4; ++c) acc[r][c] = 0.f;

    for (int k0 = 0; k0 < K; k0 += BK) {
#pragma unroll
        for (int rep = 0; rep < 2; ++rep) {
            int r  = (tid >> 3) + rep * 32;
            int kq = tid & 7;
            int grow = row0 + r;
            float4 v = make_float4(0.f, 0.f, 0.f, 0.f);
            if (grow < M)
                v = *(const float4*)(A + (size_t)grow * K + k0 + 4 * kq);
            aT[4*kq+0][r] = v.x;
            aT[4*kq+1][r] = v.y;
            aT[4*kq+2][r] = v.z;
            aT[4*kq+3][r] = v.w;
        }
#pragma unroll
        for (int rep = 0; rep < 4; ++rep) {
            int j  = tid & 127;
            int kh = tid >> 7;
            int kk = kh * 16 + rep * 4;
            float4 v = *(const float4*)(W + (size_t)j * K + k0 + kk);
            wT[kk+0][j] = v.x;
            wT[kk+1][j] = v.y;
            wT[kk+2][j] = v.z;
            wT[kk+3][j] = v.w;
        }
        __syncthreads();
#pragma unroll
        for (int k = 0; k < BK; ++k) {
            float4 w4 = *(const float4*)&wT[k][4*tx];
            float4 a0 = *(const float4*)&aT[k][8*ty];
            float4 a1 = *(const float4*)&aT[k][8*ty+4];
            float av[8] = {a0.x,a0.y,a0.z,a0.w,a1.x,a1.y,a1.z,a1.w};
            float wv[4] = {w4.x,w4.y,w4.z,w4.w};
#pragma unroll
            for (int r = 0; r < 8; ++r)
#pragma unroll
                for (int c = 0; c < 4; ++c)
                    acc[r][c] = fmaf(av[r], wv[c], acc[r][c]);
        }
        __syncthreads();
    }

#pragma unroll
    for (int r = 0; r < 8; ++r) {
        int grow = row0 + 8*ty + r;
        if (grow < M) {
            float4 o = make_float4(acc[r][0], acc[r][1], acc[r][2], acc[r][3]);
            *(float4*)(C + (size_t)grow * BN + 4*tx) = o;
        }
    }
    (void)bias; (void)prelu_a; (void)bnsum; (void)bnsumsq;
}

// ---------------------------------------------------------------------------
// K4: h = PReLU(agg @ W1^T + b1), + BN sum/sumsq.  bf16x3 MFMA, persistent,
// double-buffered global_load_lds staging.  A (agg) rows are stored with a
// 32B-segment XOR swizzle (seg ^= row&15) by gather_line so the linear LDS
// image gives near-conflict-free ds_read_b128 fragment reads.
// Output h is row-major (may alias A: each tile fully staged before write).
// ---------------------------------------------------------------------------
__global__ __launch_bounds__(512, 1) void gemm_h_kernel(
    const float* __restrict__ A,     // [M,128] fp32, seg-swizzled rows
    const float* __restrict__ W,     // [128,128] fp32 row-major
    const float* __restrict__ bias,  // [128]
    const float* __restrict__ prelu_a,
    float* __restrict__ C,           // [M,128] fp32 row-major
    float* __restrict__ bnsum, float* __restrict__ bnsumsq, int M)
{
    __shared__ float  Abuf[2][64 * 128];   // 2 x 32KB fp32 tiles
    __shared__ bf16x8 Wh[32 * 64];         // 32 frags x 64 lanes x 16B = 32KB
    __shared__ bf16x8 Wl[32 * 64];         // 32KB
    __shared__ float  red_s[128], red_q[128];

    const int tid = threadIdx.x;
    const int l   = tid & 63;
    const int w   = tid >> 6;   // wave 0..7
    const int rt  = w >> 1;     // row-tile (16 rows) 0..3
    const int ch  = w & 1;      // col half (64 cols)
    const int lr  = l & 15;
    const int ks  = l >> 4;

    // ---- stage W fragments once: wave w -> frag pairs p = 4w..4w+3
#pragma unroll
    for (int pp = 0; pp < 4; ++pp) {
        int p  = w * 4 + pp;          // p = kc*8 + n
        int kc = p >> 3, n = p & 7;
        int col = n * 16 + lr;        // B[k][col] = W[col][k]
        int k0  = kc * 32 + ks * 8;
        const float* wp = W + (size_t)col * 128 + k0;
        float f[8];
        *(float4*)&f[0] = *(const float4*)wp;
        *(float4*)&f[4] = *(const float4*)(wp + 4);
        bf16x8 hi, lo;
        split8(f, hi, lo);
        Wh[p * 64 + l] = hi;
        Wl[p * 64 + l] = lo;
    }

    const int T = (M + 63) / 64;
    const float pa = prelu_a[0];
    float b_c[4];
#pragma unroll
    for (int nn = 0; nn < 4; ++nn) b_c[nn] = bias[ch * 64 + nn * 16 + lr];

    float lsum[4] = {0.f,0.f,0.f,0.f}, lsq[4] = {0.f,0.f,0.f,0.f};

    const int t0 = blockIdx.x;
    const int G  = gridDim.x;

    // stage a 64x128 fp32 tile (32KB): 512 thr x 4 x 16B, linear per wave
    auto stage = [&](int buf, int t) {
#pragma unroll
        for (int p = 0; p < 4; ++p) {
            int chunk = p * 512 + tid;          // 0..2047 (16B units)
            int row   = chunk >> 5;             // row-in-tile
            long grow = (long)t * 64 + row;
            if (grow >= M) grow = M - 1;        // clamp (garbage ok, masked)
            const char* src = (const char*)A + grow * 512 + (size_t)(chunk & 31) * 16;
            char* dst = (char*)&Abuf[buf][0] + (size_t)chunk * 16;
            GLD16(dst, src);
        }
    };

    if (t0 < T) stage(0, t0);
    __syncthreads();   // drains vmcnt (A tile) + lgkmcnt (W frags)

    for (int i = 0, t = t0; t < T; ++i, t += G) {
        int cur = i & 1;
        int tn = t + G;
        if (tn < T) stage(cur ^ 1, tn);   // async prefetch next tile

        f32x4 acc[4];
#pragma unroll
        for (int nn = 0; nn < 4; ++nn) acc[nn] = (f32x4){0.f,0.f,0.f,0.f};

        const float* Ab = &Abuf[cur][0];
        const int r = rt * 16 + lr;       // A-frag row (row&15 == lr)
#pragma unroll
        for (int kc = 0; kc < 4; ++kc) {
            int seg = (kc * 4 + ks) ^ lr; // undo gather_line's seg swizzle
            const float* ap = Ab + r * 128 + seg * 8;
            float f[8];
            *(float4*)&f[0] = *(const float4*)ap;
            *(float4*)&f[4] = *(const float4*)(ap + 4);
            bf16x8 ah, al;
            split8(f, ah, al);
#pragma unroll
            for (int nn = 0; nn < 4; ++nn) {
                int p = kc * 8 + (ch * 4 + nn);
                bf16x8 bh = Wh[p * 64 + l];
                bf16x8 bl = Wl[p * 64 + l];
                acc[nn] = __builtin_amdgcn_mfma_f32_16x16x32_bf16(ah, bh, acc[nn], 0, 0, 0);
                acc[nn] = __builtin_amdgcn_mfma_f32_16x16x32_bf16(ah, bl, acc[nn], 0, 0, 0);
                acc[nn] = __builtin_amdgcn_mfma_f32_16x16x32_bf16(al, bh, acc[nn], 0, 0, 0);
            }
        }

        // epilogue: bias + PReLU + store + BN partial sums (row-major C)
#pragma unroll
        for (int nn = 0; nn < 4; ++nn) {
            int col = ch * 64 + nn * 16 + lr;
#pragma unroll
            for (int reg = 0; reg < 4; ++reg) {
                long grow = (long)t * 64 + rt * 16 + ks * 4 + reg;
                if (grow < M) {
                    float v = acc[nn][reg] + b_c[nn];
                    v = (v >= 0.f) ? v : pa * v;
                    C[grow * 128 + col] = v;
                    lsum[nn] += v;
                    lsq[nn]  += v * v;
                }
            }
        }
        __syncthreads();   // next tile staged; all waves done with Abuf[cur]
    }

    // ---- block-level BN reduction, one global atomic per feature
    if (tid < 128) { red_s[tid] = 0.f; red_q[tid] = 0.f; }
    __syncthreads();
#pragma unroll
    for (int nn = 0; nn < 4; ++nn) {
        int col = ch * 64 + nn * 16 + lr;
        atomicAdd(&red_s[col], lsum[nn]);
        atomicAdd(&red_q[col], lsq[nn]);
    }
    __syncthreads();
    if (tid < 128) {
        atomicAdd(&bnsum[tid],   red_s[tid]);
        atomicAdd(&bnsumsq[tid], red_q[tid]);
    }
}

// ---------------------------------------------------------------------------
// fused[e] = edge_attr[e] + 0.5*(px[src[e]] + px[dst[e]])   (float4 elements)
// ---------------------------------------------------------------------------
__global__ __launch_bounds__(256) void fuse_kernel(
    const float* __restrict__ edge_attr, const float* __restrict__ px,
    const int* __restrict__ src, const int* __restrict__ dst,
    float* __restrict__ fused, int E)
{
    size_t i = (size_t)blockIdx.x * blockDim.x + threadIdx.x;
    size_t total = (size_t)E * 32;   // float4s per edge row (128 floats)
    if (i >= total) return;
    int e = (int)(i >> 5);
    int q = (int)(i & 31);
    int s = src[e], d = dst[e];
    float4 ea = ((const float4*)edge_attr)[i];
    float4 ps = ((const float4*)px)[(size_t)s * 32 + q];
    float4 pd = ((const float4*)px)[(size_t)d * 32 + q];
    float4 o;
    o.x = ea.x + 0.5f * (ps.x + pd.x);
    o.y = ea.y + 0.5f * (ps.y + pd.y);
    o.z = ea.z + 0.5f * (ps.z + pd.z);
    o.w = ea.w + 0.5f * (ps.w + pd.w);
    ((float4*)fused)[i] = o;
}

// ---------------------------------------------------------------------------
// CSR build: histogram -> block-scan -> global scan -> add+copy -> fill
// ---------------------------------------------------------------------------
__global__ __launch_bounds__(256) void hist_kernel(
    const int* __restrict__ idx, int* __restrict__ deg, int n)
{
    int i = blockIdx.x * 256 + threadIdx.x;
    if (i < n) atomicAdd(&deg[idx[i]], 1);
}

__global__ __launch_bounds__(256) void scan_local_kernel(
    const int* __restrict__ deg, int* __restrict__ excl,
    int* __restrict__ bsum, int n)
{
    __shared__ int ts[256];
    int t = threadIdx.x;
    int base = blockIdx.x * 2048 + t * 8;
    int v[8]; int s = 0;
#pragma unroll
    for (int j = 0; j < 8; ++j) { v[j] = (base + j < n) ? deg[base + j] : 0; s += v[j]; }
    ts[t] = s; __syncthreads();
    for (int off = 1; off < 256; off <<= 1) {
        int x = (t >= off) ? ts[t - off] : 0;
        __syncthreads();
        ts[t] += x;
        __syncthreads();
    }
    if (t == 255) bsum[blockIdx.x] = ts[255];
    int run = ts[t] - s;
#pragma unroll
    for (int j = 0; j < 8; ++j) {
        if (base + j < n) excl[base + j] = run;
        run += v[j];
    }
}

__global__ __launch_bounds__(256) void scan_blocks_kernel(int* __restrict__ bsum, int nb)
{
    __shared__ int ts[256];
    __shared__ int carry_s;
    int t = threadIdx.x;
    if (t == 0) carry_s = 0;
    __syncthreads();
    for (int c0 = 0; c0 < nb; c0 += 256) {
        int v = (c0 + t < nb) ? bsum[c0 + t] : 0;
        ts[t] = v; __syncthreads();
        for (int off = 1; off < 256; off <<= 1) {
            int x = (t >= off) ? ts[t - off] : 0;
            __syncthreads();
            ts[t] += x;
            __syncthreads();
        }
        int carry = carry_s;
        if (c0 + t < nb) bsum[c0 + t] = carry + ts[t] - v;
        int tot = ts[255];
        __syncthreads();
        if (t == 0) carry_s = carry + tot;
        __syncthreads();
    }
}

__global__ __launch_bounds__(256) void scan_add_kernel(
    int* __restrict__ rowptr, const int* __restrict__ bsum,
    int* __restrict__ cursor, int n, int total)
{
    int i = blockIdx.x * 256 + threadIdx.x;
    if (i == 0) rowptr[n] = total;
    if (i >= n) return;
    int v = rowptr[i] + bsum[i >> 11];
    rowptr[i] = v;
    cursor[i] = v;
}

__global__ __launch_bounds__(256) void fill_kernel(
    const int* __restrict__ dsti, const int* __restrict__ vals,
    int* __restrict__ cursor, int* __restrict__ adj, int n)
{
    int i = blockIdx.x * 256 + threadIdx.x;
    if (i >= n) return;
    int pos = atomicAdd(&cursor[dsti[i]], 1);
    adj[pos] = vals ? vals[i] : i;
}

// ---------------------------------------------------------------------------
// agg[e] = mean over incoming line-edges of fused[src]; one wave per edge.
// Writes agg rows with 32B-segment swizzle: seg' = seg ^ (e & 15)  (the
// bf16x3 GEMM's LDS fragment reads undo this; full 512B row still written
// contiguously per wave -> coalescing unchanged).
// ---------------------------------------------------------------------------
__global__ __launch_bounds__(256) void gather_line_kernel(
    const float* __restrict__ fused, const int* __restrict__ rowptr,
    const int* __restrict__ adj, float* __restrict__ agg, int E)
{
    int w = (int)(((size_t)blockIdx.x * 256 + threadIdx.x) >> 6);
    int lane = threadIdx.x & 63;
    if (w >= E) return;
    int s0 = rowptr[w], s1 = rowptr[w + 1];
    float2 acc = make_float2(0.f, 0.f);
    for (int j = s0; j < s1; ++j) {
        int s = adj[j];
        float2 v = ((const float2*)(fused + (size_t)s * 128))[lane];
        acc.x += v.x; acc.y += v.y;
    }
    float scl = 1.f / fmaxf((float)(s1 - s0), 1.f);
    int seg = lane >> 2;
    int sw  = seg ^ (w & 15);
    *(float2*)((char*)agg + (size_t)w * 512 + ((size_t)sw << 5) + ((size_t)(lane & 3) << 3))
        = make_float2(acc.x * scl, acc.y * scl);
}

// ---------------------------------------------------------------------------
// BN finalize: cA = gamma/sqrt(var+eps); cB = beta - mean*cA
// ---------------------------------------------------------------------------
__global__ void bn_finalize_kernel(
    const float* __restrict__ bnsum, const float* __restrict__ bnsumsq,
    const float* __restrict__ gamma, const float* __restrict__ beta,
    float* __restrict__ cA, float* __restrict__ cB, float invE)
{
    int c = threadIdx.x;  // 128 threads
    float mean = bnsum[c] * invE;
    float var  = bnsumsq[c] * invE - mean * mean;
    float istd = 1.f / sqrtf(var + BN_EPS);
    float a = istd * gamma[c];
    cA[c] = a;
    cB[c] = beta[c] - mean * a;
}

// ---------------------------------------------------------------------------
// out[n] = mean over incident edges of (fused[e] + h[e]*cA + cB);
// one wave per node.  (h is row-major.)
// ---------------------------------------------------------------------------
__global__ __launch_bounds__(256) void gather_node_kernel(
    const float* __restrict__ fused, const float* __restrict__ h,
    const int* __restrict__ rowptr, const int* __restrict__ adj,
    const float* __restrict__ cA, const float* __restrict__ cB,
    float* __restrict__ out, int N)
{
    int w = (int)(((size_t)blockIdx.x * 256 + threadIdx.x) >> 6);
    int lane = threadIdx.x & 63;
    if (w >= N) return;
    int s0 = rowptr[w], s1 = rowptr[w + 1];
    float2 A = ((const float2*)cA)[lane];
    float2 B = ((const float2*)cB)[lane];
    float2 acc = make_float2(0.f, 0.f);
    for (int j = s0; j < s1; ++j) {
        int e = adj[j];
        float2 f  = ((const float2*)(fused + (size_t)e * 128))[lane];
        float2 hh = ((const float2*)(h     + (size_t)e * 128))[lane];
        acc.x += f.x + fmaf(hh.x, A.x, B.x);
        acc.y += f.y + fmaf(hh.y, A.y, B.y);
    }
    float scl = 1.f / fmaxf((float)(s1 - s0), 1.f);
    ((float2*)(out + (size_t)w * 128))[lane] = make_float2(acc.x * scl, acc.y * scl);
}

// ---------------------------------------------------------------------------
extern "C" void kernel_launch(void* const* d_in, const int* in_sizes, int n_in,
                              void* d_out, int out_size, void* d_ws, size_t ws_size,
                              hipStream_t stream) {
    const float* x     = (const float*)d_in[0];
    const float* ea    = (const float*)d_in[1];
    const float* Wp    = (const float*)d_in[2];  // [128, 256]
    const float* W1    = (const float*)d_in[3];  // [128, 128]
    const float* b1    = (const float*)d_in[4];
    const float* pa    = (const float*)d_in[5];
    const float* gamma = (const float*)d_in[6];
    const float* beta  = (const float*)d_in[7];
    const int*   ei    = (const int*)d_in[8];
    const int*   lg    = (const int*)d_in[9];

    const int ND = 256, ED = 128;
    const int N = in_sizes[0] / ND;   // 50000
    const int E = in_sizes[1] / ED;   // 800000
    const int L = in_sizes[9] / 2;    // 1600000
    const int* src  = ei;
    const int* dstI = ei + E;
    const int* ls   = lg;
    const int* ld   = lg + L;

    float* ws = (float*)d_ws;
    size_t off = 0;
    float* px    = ws + off; off += (size_t)N * ED;       // 6.4M
    float* fused = ws + off; off += (size_t)E * ED;       // 102.4M
    float* aggh  = ws + off; off += (size_t)E * ED;       // 102.4M (agg, then h in-place)
    float* bnsum = ws + off; off += ED;
    float* bnsq  = ws + off; off += ED;
    float* cA    = ws + off; off += ED;
    float* cB    = ws + off; off += ED;

    int* iws = (int*)(ws + off);
    size_t ioff = 0;
    int* deg_l  = iws + ioff; ioff += E;        // reused as cursor
    int* rp_l   = iws + ioff; ioff += E + 1;
    int* adj_l  = iws + ioff; ioff += L;
    int* bs_l   = iws + ioff; ioff += 1024;
    int* deg_n  = iws + ioff; ioff += N;        // reused as cursor
    int* rp_n   = iws + ioff; ioff += N + 1;
    int* adj_n  = iws + ioff; ioff += E;
    int* bs_n   = iws + ioff; ioff += 1024;

    float* out = (float*)d_out;

    const int nb_l = (E + 2047) / 2048;
    const int nb_n = (N + 2047) / 2048;

    hipMemsetAsync(bnsum, 0, 2 * ED * sizeof(float), stream);  // bnsum+bnsq
    hipMemsetAsync(deg_l, 0, (size_t)E * sizeof(int), stream);
    hipMemsetAsync(deg_n, 0, (size_t)N * sizeof(int), stream);

    // K1: px = x @ Wp^T
    gemm_kernel<256, false><<<(N + 63) / 64, 256, 0, stream>>>(
        x, Wp, nullptr, nullptr, px, nullptr, nullptr, N);

    // K2: fused = edge_attr + 0.5*(px[src]+px[dst])
    {
        size_t tot = (size_t)E * 32;
        fuse_kernel<<<(int)((tot + 255) / 256), 256, 0, stream>>>(ea, px, src, dstI, fused, E);
    }

    // ---- line-graph CSR (bucket by destination edge ld)
    hist_kernel<<<(L + 255) / 256, 256, 0, stream>>>(ld, deg_l, L);
    scan_local_kernel<<<nb_l, 256, 0, stream>>>(deg_l, rp_l, bs_l, E);
    scan_blocks_kernel<<<1, 256, 0, stream>>>(bs_l, nb_l);
    scan_add_kernel<<<(E + 255) / 256, 256, 0, stream>>>(rp_l, bs_l, deg_l, E, L);
    fill_kernel<<<(L + 255) / 256, 256, 0, stream>>>(ld, ls, deg_l, adj_l, L);

    // ---- node CSR (bucket by dst)
    hist_kernel<<<(E + 255) / 256, 256, 0, stream>>>(dstI, deg_n, E);
    scan_local_kernel<<<nb_n, 256, 0, stream>>>(deg_n, rp_n, bs_n, N);
    scan_blocks_kernel<<<1, 256, 0, stream>>>(bs_n, nb_n);
    scan_add_kernel<<<(N + 255) / 256, 256, 0, stream>>>(rp_n, bs_n, deg_n, N, E);
    fill_kernel<<<(E + 255) / 256, 256, 0, stream>>>(dstI, nullptr, deg_n, adj_n, E);

    // K3: agg = segment-mean of fused over line graph (seg-swizzled rows)
    gather_line_kernel<<<(E + 3) / 4, 256, 0, stream>>>(fused, rp_l, adj_l, aggh, E);

    // K4: h = PReLU(agg @ W1^T + b1) + BN sums  (bf16x3 MFMA, in-place)
    gemm_h_kernel<<<256, 512, 0, stream>>>(aggh, W1, b1, pa, aggh, bnsum, bnsq, E);

    // K4b: BN coefficients
    bn_finalize_kernel<<<1, 128, 0, stream>>>(bnsum, bnsq, gamma, beta, cA, cB, 1.f / (float)E);

    // K5: out = segment-mean over dst of (fused + BN(h))  (no atomics)
    gather_node_kernel<<<(N + 3) / 4, 256, 0, stream>>>(fused, aggh, rp_n, adj_n, cA, cB, out, N);
}

// Round 2
// 1710.974 us; speedup vs baseline: 1.2138x; 1.0542x over previous
//
#include <hip/hip_runtime.h>
#include <cstdint>

#define BN_EPS 1e-5f

typedef __attribute__((ext_vector_type(8))) short bf16x8;
typedef __attribute__((ext_vector_type(4))) float f32x4;

// async 16B global -> LDS (linear: wave-uniform base + lane*16)
#define GLD16(dst, src)                                                        \
  __builtin_amdgcn_global_load_lds(                                            \
      (const __attribute__((address_space(1))) void*)(src),                    \
      (__attribute__((address_space(3))) void*)(dst), 16, 0, 0)

// truncation split: f = hi + lo + O(2^-17 rel); hi/lo exact bf16
__device__ inline void split8(const float* f, bf16x8& hi, bf16x8& lo) {
#pragma unroll
  for (int j = 0; j < 8; ++j) {
    unsigned u = __float_as_uint(f[j]);
    hi[j] = (short)(u >> 16);
    float r = f[j] - __uint_as_float(u & 0xFFFF0000u);
    lo[j] = (short)(__float_as_uint(r) >> 16);
  }
}

// ---------------------------------------------------------------------------
// Tiled fp32 GEMM: C[M x 128] = A[M x K] @ W[128 x K]^T  (kept for K1: px)
// ---------------------------------------------------------------------------
template<int K, bool EPI>
__global__ __launch_bounds__(256) void gemm_kernel(
    const float* __restrict__ A,
    const float* __restrict__ W,      // [128, K] row-major
    const float* __restrict__ bias,
    const float* __restrict__ prelu_a,
    float* __restrict__ C,            // [M, 128]
    float* __restrict__ bnsum,
    float* __restrict__ bnsumsq,
    int M)
{
    constexpr int BM = 64, BN = 128, BK = 32;
    __shared__ float aT[BK][BM + 4];
    __shared__ float wT[BK][BN];

    const int tid = threadIdx.x;
    const int tx = tid & 31;
    const int ty = tid >> 5;
    const int row0 = blockIdx.x * BM;

    float acc[8][4];
#pragma unroll
    for (int r = 0; r < 8; ++r)
#pragma unroll
        for (int c = 0; c < 4; ++c) acc[r][c] = 0.f;

    for (int k0 = 0; k0 < K; k0 += BK) {
#pragma unroll
        for (int rep = 0; rep < 2; ++rep) {
            int r  = (tid >> 3) + rep * 32;
            int kq = tid & 7;
            int grow = row0 + r;
            float4 v = make_float4(0.f, 0.f, 0.f, 0.f);
            if (grow < M)
                v = *(const float4*)(A + (size_t)grow * K + k0 + 4 * kq);
            aT[4*kq+0][r] = v.x;
            aT[4*kq+1][r] = v.y;
            aT[4*kq+2][r] = v.z;
            aT[4*kq+3][r] = v.w;
        }
#pragma unroll
        for (int rep = 0; rep < 4; ++rep) {
            int j  = tid & 127;
            int kh = tid >> 7;
            int kk = kh * 16 + rep * 4;
            float4 v = *(const float4*)(W + (size_t)j * K + k0 + kk);
            wT[kk+0][j] = v.x;
            wT[kk+1][j] = v.y;
            wT[kk+2][j] = v.z;
            wT[kk+3][j] = v.w;
        }
        __syncthreads();
#pragma unroll
        for (int k = 0; k < BK; ++k) {
            float4 w4 = *(const float4*)&wT[k][4*tx];
            float4 a0 = *(const float4*)&aT[k][8*ty];
            float4 a1 = *(const float4*)&aT[k][8*ty+4];
            float av[8] = {a0.x,a0.y,a0.z,a0.w,a1.x,a1.y,a1.z,a1.w};
            float wv[4] = {w4.x,w4.y,w4.z,w4.w};
#pragma unroll
            for (int r = 0; r < 8; ++r)
#pragma unroll
                for (int c = 0; c < 4; ++c)
                    acc[r][c] = fmaf(av[r], wv[c], acc[r][c]);
        }
        __syncthreads();
    }

#pragma unroll
    for (int r = 0; r < 8; ++r) {
        int grow = row0 + 8*ty + r;
        if (grow < M) {
            float4 o = make_float4(acc[r][0], acc[r][1], acc[r][2], acc[r][3]);
            *(float4*)(C + (size_t)grow * BN + 4*tx) = o;
        }
    }
    (void)bias; (void)prelu_a; (void)bnsum; (void)bnsumsq;
}

// ---------------------------------------------------------------------------
// K4: h = PReLU(agg @ W1^T + b1), + BN sum/sumsq.  bf16x3 MFMA, persistent,
// double-buffered global_load_lds staging.  A (agg) rows are stored with a
// 32B-segment XOR swizzle (seg ^= row&15) by gather_line so the linear LDS
// image gives near-conflict-free ds_read_b128 fragment reads.
// ---------------------------------------------------------------------------
__global__ __launch_bounds__(512, 1) void gemm_h_kernel(
    const float* __restrict__ A,     // [M,128] fp32, seg-swizzled rows
    const float* __restrict__ W,     // [128,128] fp32 row-major
    const float* __restrict__ bias,  // [128]
    const float* __restrict__ prelu_a,
    float* __restrict__ C,           // [M,128] fp32 row-major
    float* __restrict__ bnsum, float* __restrict__ bnsumsq, int M)
{
    __shared__ float  Abuf[2][64 * 128];   // 2 x 32KB fp32 tiles
    __shared__ bf16x8 Wh[32 * 64];         // 32KB
    __shared__ bf16x8 Wl[32 * 64];         // 32KB
    __shared__ float  red_s[128], red_q[128];

    const int tid = threadIdx.x;
    const int l   = tid & 63;
    const int w   = tid >> 6;   // wave 0..7
    const int rt  = w >> 1;     // row-tile (16 rows) 0..3
    const int ch  = w & 1;      // col half (64 cols)
    const int lr  = l & 15;
    const int ks  = l >> 4;

#pragma unroll
    for (int pp = 0; pp < 4; ++pp) {
        int p  = w * 4 + pp;          // p = kc*8 + n
        int kc = p >> 3, n = p & 7;
        int col = n * 16 + lr;        // B[k][col] = W[col][k]
        int k0  = kc * 32 + ks * 8;
        const float* wp = W + (size_t)col * 128 + k0;
        float f[8];
        *(float4*)&f[0] = *(const float4*)wp;
        *(float4*)&f[4] = *(const float4*)(wp + 4);
        bf16x8 hi, lo;
        split8(f, hi, lo);
        Wh[p * 64 + l] = hi;
        Wl[p * 64 + l] = lo;
    }

    const int T = (M + 63) / 64;
    const float pa = prelu_a[0];
    float b_c[4];
#pragma unroll
    for (int nn = 0; nn < 4; ++nn) b_c[nn] = bias[ch * 64 + nn * 16 + lr];

    float lsum[4] = {0.f,0.f,0.f,0.f}, lsq[4] = {0.f,0.f,0.f,0.f};

    const int t0 = blockIdx.x;
    const int G  = gridDim.x;

    auto stage = [&](int buf, int t) {
#pragma unroll
        for (int p = 0; p < 4; ++p) {
            int chunk = p * 512 + tid;
            int row   = chunk >> 5;
            long grow = (long)t * 64 + row;
            if (grow >= M) grow = M - 1;
            const char* src = (const char*)A + grow * 512 + (size_t)(chunk & 31) * 16;
            char* dst = (char*)&Abuf[buf][0] + (size_t)chunk * 16;
            GLD16(dst, src);
        }
    };

    if (t0 < T) stage(0, t0);
    __syncthreads();

    for (int i = 0, t = t0; t < T; ++i, t += G) {
        int cur = i & 1;
        int tn = t + G;
        if (tn < T) stage(cur ^ 1, tn);

        f32x4 acc[4];
#pragma unroll
        for (int nn = 0; nn < 4; ++nn) acc[nn] = (f32x4){0.f,0.f,0.f,0.f};

        const float* Ab = &Abuf[cur][0];
        const int r = rt * 16 + lr;
#pragma unroll
        for (int kc = 0; kc < 4; ++kc) {
            int seg = (kc * 4 + ks) ^ lr;
            const float* ap = Ab + r * 128 + seg * 8;
            float f[8];
            *(float4*)&f[0] = *(const float4*)ap;
            *(float4*)&f[4] = *(const float4*)(ap + 4);
            bf16x8 ah, al;
            split8(f, ah, al);
#pragma unroll
            for (int nn = 0; nn < 4; ++nn) {
                int p = kc * 8 + (ch * 4 + nn);
                bf16x8 bh = Wh[p * 64 + l];
                bf16x8 bl = Wl[p * 64 + l];
                acc[nn] = __builtin_amdgcn_mfma_f32_16x16x32_bf16(ah, bh, acc[nn], 0, 0, 0);
                acc[nn] = __builtin_amdgcn_mfma_f32_16x16x32_bf16(ah, bl, acc[nn], 0, 0, 0);
                acc[nn] = __builtin_amdgcn_mfma_f32_16x16x32_bf16(al, bh, acc[nn], 0, 0, 0);
            }
        }

#pragma unroll
        for (int nn = 0; nn < 4; ++nn) {
            int col = ch * 64 + nn * 16 + lr;
#pragma unroll
            for (int reg = 0; reg < 4; ++reg) {
                long grow = (long)t * 64 + rt * 16 + ks * 4 + reg;
                if (grow < M) {
                    float v = acc[nn][reg] + b_c[nn];
                    v = (v >= 0.f) ? v : pa * v;
                    C[grow * 128 + col] = v;
                    lsum[nn] += v;
                    lsq[nn]  += v * v;
                }
            }
        }
        __syncthreads();
    }

    if (tid < 128) { red_s[tid] = 0.f; red_q[tid] = 0.f; }
    __syncthreads();
#pragma unroll
    for (int nn = 0; nn < 4; ++nn) {
        int col = ch * 64 + nn * 16 + lr;
        atomicAdd(&red_s[col], lsum[nn]);
        atomicAdd(&red_q[col], lsq[nn]);
    }
    __syncthreads();
    if (tid < 128) {
        atomicAdd(&bnsum[tid],   red_s[tid]);
        atomicAdd(&bnsumsq[tid], red_q[tid]);
    }
}

// ---------------------------------------------------------------------------
// fused[e] = edge_attr[e] + 0.5*(px[src[e]] + px[dst[e]])   (float4 elements)
// ---------------------------------------------------------------------------
__global__ __launch_bounds__(256) void fuse_kernel(
    const float* __restrict__ edge_attr, const float* __restrict__ px,
    const int* __restrict__ src, const int* __restrict__ dst,
    float* __restrict__ fused, int E)
{
    size_t i = (size_t)blockIdx.x * blockDim.x + threadIdx.x;
    size_t total = (size_t)E * 32;
    if (i >= total) return;
    int e = (int)(i >> 5);
    int q = (int)(i & 31);
    int s = src[e], d = dst[e];
    float4 ea = ((const float4*)edge_attr)[i];
    float4 ps = ((const float4*)px)[(size_t)s * 32 + q];
    float4 pd = ((const float4*)px)[(size_t)d * 32 + q];
    float4 o;
    o.x = ea.x + 0.5f * (ps.x + pd.x);
    o.y = ea.y + 0.5f * (ps.y + pd.y);
    o.z = ea.z + 0.5f * (ps.z + pd.z);
    o.w = ea.w + 0.5f * (ps.w + pd.w);
    ((float4*)fused)[i] = o;
}

// ---------------------------------------------------------------------------
// CSR build: histogram -> block-scan -> global scan -> add+copy -> fill
// ---------------------------------------------------------------------------
__global__ __launch_bounds__(256) void hist_kernel(
    const int* __restrict__ idx, int* __restrict__ deg, int n)
{
    int i = blockIdx.x * 256 + threadIdx.x;
    if (i < n) atomicAdd(&deg[idx[i]], 1);
}

__global__ __launch_bounds__(256) void scan_local_kernel(
    const int* __restrict__ deg, int* __restrict__ excl,
    int* __restrict__ bsum, int n)
{
    __shared__ int ts[256];
    int t = threadIdx.x;
    int base = blockIdx.x * 2048 + t * 8;
    int v[8]; int s = 0;
#pragma unroll
    for (int j = 0; j < 8; ++j) { v[j] = (base + j < n) ? deg[base + j] : 0; s += v[j]; }
    ts[t] = s; __syncthreads();
    for (int off = 1; off < 256; off <<= 1) {
        int x = (t >= off) ? ts[t - off] : 0;
        __syncthreads();
        ts[t] += x;
        __syncthreads();
    }
    if (t == 255) bsum[blockIdx.x] = ts[255];
    int run = ts[t] - s;
#pragma unroll
    for (int j = 0; j < 8; ++j) {
        if (base + j < n) excl[base + j] = run;
        run += v[j];
    }
}

__global__ __launch_bounds__(256) void scan_blocks_kernel(int* __restrict__ bsum, int nb)
{
    __shared__ int ts[256];
    __shared__ int carry_s;
    int t = threadIdx.x;
    if (t == 0) carry_s = 0;
    __syncthreads();
    for (int c0 = 0; c0 < nb; c0 += 256) {
        int v = (c0 + t < nb) ? bsum[c0 + t] : 0;
        ts[t] = v; __syncthreads();
        for (int off = 1; off < 256; off <<= 1) {
            int x = (t >= off) ? ts[t - off] : 0;
            __syncthreads();
            ts[t] += x;
            __syncthreads();
        }
        int carry = carry_s;
        if (c0 + t < nb) bsum[c0 + t] = carry + ts[t] - v;
        int tot = ts[255];
        __syncthreads();
        if (t == 0) carry_s = carry + tot;
        __syncthreads();
    }
}

__global__ __launch_bounds__(256) void scan_add_kernel(
    int* __restrict__ rowptr, const int* __restrict__ bsum,
    int* __restrict__ cursor, int n, int total)
{
    int i = blockIdx.x * 256 + threadIdx.x;
    if (i == 0) rowptr[n] = total;
    if (i >= n) return;
    int v = rowptr[i] + bsum[i >> 11];
    rowptr[i] = v;
    cursor[i] = v;
}

__global__ __launch_bounds__(256) void fill_kernel(
    const int* __restrict__ dsti, const int* __restrict__ vals,
    int* __restrict__ cursor, int* __restrict__ adj, int n)
{
    int i = blockIdx.x * 256 + threadIdx.x;
    if (i >= n) return;
    int pos = atomicAdd(&cursor[dsti[i]], 1);
    adj[pos] = vals ? vals[i] : i;
}

// ---------------------------------------------------------------------------
// agg[e] = mean over incoming line-edges of fused[src]; one wave per edge.
// MLP version: lane-parallel adjacency load + batched (4) row loads.
// Writes agg rows with 32B-segment swizzle: seg' = seg ^ (e & 15).
// ---------------------------------------------------------------------------
__global__ __launch_bounds__(256) void gather_line_kernel(
    const float* __restrict__ fused, const int* __restrict__ rowptr,
    const int* __restrict__ adj, float* __restrict__ agg, int E)
{
    int w = (int)(((size_t)blockIdx.x * 256 + threadIdx.x) >> 6);
    int lane = threadIdx.x & 63;
    if (w >= E) return;
    int s0 = rowptr[w], s1 = rowptr[w + 1];
    int deg = s1 - s0;

    // one coalesced adjacency load covers deg <= 64 (typical deg ~2)
    int myadj = (s0 + lane < s1) ? adj[s0 + lane] : 0;

    float2 acc = make_float2(0.f, 0.f);
    int cnt = min(deg, 64);
    for (int k = 0; k < cnt; k += 4) {
        int b  = cnt - k;
        int lastk = cnt - 1;
        int e0 = __shfl(myadj, k);
        int e1 = __shfl(myadj, min(k + 1, lastk));
        int e2 = __shfl(myadj, min(k + 2, lastk));
        int e3 = __shfl(myadj, min(k + 3, lastk));
        // 4 independent row loads in flight (dups for short tails hit L1)
        float2 v0 = ((const float2*)(fused + (size_t)e0 * 128))[lane];
        float2 v1 = ((const float2*)(fused + (size_t)e1 * 128))[lane];
        float2 v2 = ((const float2*)(fused + (size_t)e2 * 128))[lane];
        float2 v3 = ((const float2*)(fused + (size_t)e3 * 128))[lane];
        acc.x += v0.x; acc.y += v0.y;
        if (b > 1) { acc.x += v1.x; acc.y += v1.y; }
        if (b > 2) { acc.x += v2.x; acc.y += v2.y; }
        if (b > 3) { acc.x += v3.x; acc.y += v3.y; }
    }
    // overflow (deg > 64) — essentially never
    for (int j = s0 + 64; j < s1; ++j) {
        int e = adj[j];
        float2 v = ((const float2*)(fused + (size_t)e * 128))[lane];
        acc.x += v.x; acc.y += v.y;
    }

    float scl = 1.f / fmaxf((float)deg, 1.f);
    int seg = lane >> 2;
    int sw  = seg ^ (w & 15);
    *(float2*)((char*)agg + (size_t)w * 512 + ((size_t)sw << 5) + ((size_t)(lane & 3) << 3))
        = make_float2(acc.x * scl, acc.y * scl);
}

// ---------------------------------------------------------------------------
// BN finalize: cA = gamma/sqrt(var+eps); cB = beta - mean*cA
// ---------------------------------------------------------------------------
__global__ void bn_finalize_kernel(
    const float* __restrict__ bnsum, const float* __restrict__ bnsumsq,
    const float* __restrict__ gamma, const float* __restrict__ beta,
    float* __restrict__ cA, float* __restrict__ cB, float invE)
{
    int c = threadIdx.x;  // 128 threads
    float mean = bnsum[c] * invE;
    float var  = bnsumsq[c] * invE - mean * mean;
    float istd = 1.f / sqrtf(var + BN_EPS);
    float a = istd * gamma[c];
    cA[c] = a;
    cB[c] = beta[c] - mean * a;
}

// ---------------------------------------------------------------------------
// out[n] = mean over incident edges of (fused[e] + h[e]*cA + cB);
// one wave per node.  MLP version: lane-parallel adj + batched (4) loads,
// coefficients hoisted: sum(f + h*A + B) = sum(f) + A*sum(h) + deg*B.
// ---------------------------------------------------------------------------
__global__ __launch_bounds__(256) void gather_node_kernel(
    const float* __restrict__ fused, const float* __restrict__ h,
    const int* __restrict__ rowptr, const int* __restrict__ adj,
    const float* __restrict__ cA, const float* __restrict__ cB,
    float* __restrict__ out, int N)
{
    int w = (int)(((size_t)blockIdx.x * 256 + threadIdx.x) >> 6);
    int lane = threadIdx.x & 63;
    if (w >= N) return;
    int s0 = rowptr[w], s1 = rowptr[w + 1];
    int deg = s1 - s0;
    float2 A = ((const float2*)cA)[lane];
    float2 B = ((const float2*)cB)[lane];

    float2 accf = make_float2(0.f, 0.f);
    float2 acch = make_float2(0.f, 0.f);

    for (int base = s0; base < s1; base += 64) {
        int chunk = min(s1 - base, 64);
        int myadj = (base + lane < s1) ? adj[base + lane] : 0;
        for (int k = 0; k < chunk; k += 4) {
            int b = chunk - k;
            int lastk = chunk - 1;
            int e0 = __shfl(myadj, k);
            int e1 = __shfl(myadj, min(k + 1, lastk));
            int e2 = __shfl(myadj, min(k + 2, lastk));
            int e3 = __shfl(myadj, min(k + 3, lastk));
            // 8 independent loads in flight
            float2 f0 = ((const float2*)(fused + (size_t)e0 * 128))[lane];
            float2 h0 = ((const float2*)(h     + (size_t)e0 * 128))[lane];
            float2 f1 = ((const float2*)(fused + (size_t)e1 * 128))[lane];
            float2 h1 = ((const float2*)(h     + (size_t)e1 * 128))[lane];
            float2 f2 = ((const float2*)(fused + (size_t)e2 * 128))[lane];
            float2 h2 = ((const float2*)(h     + (size_t)e2 * 128))[lane];
            float2 f3 = ((const float2*)(fused + (size_t)e3 * 128))[lane];
            float2 h3 = ((const float2*)(h     + (size_t)e3 * 128))[lane];
            accf.x += f0.x; accf.y += f0.y; acch.x += h0.x; acch.y += h0.y;
            if (b > 1) { accf.x += f1.x; accf.y += f1.y; acch.x += h1.x; acch.y += h1.y; }
            if (b > 2) { accf.x += f2.x; accf.y += f2.y; acch.x += h2.x; acch.y += h2.y; }
            if (b > 3) { accf.x += f3.x; accf.y += f3.y; acch.x += h3.x; acch.y += h3.y; }
        }
    }

    float scl = 1.f / fmaxf((float)deg, 1.f);
    float2 o;
    o.x = (accf.x + fmaf(acch.x, A.x, (float)deg * B.x)) * scl;
    o.y = (accf.y + fmaf(acch.y, A.y, (float)deg * B.y)) * scl;
    ((float2*)(out + (size_t)w * 128))[lane] = o;
}

// ---------------------------------------------------------------------------
extern "C" void kernel_launch(void* const* d_in, const int* in_sizes, int n_in,
                              void* d_out, int out_size, void* d_ws, size_t ws_size,
                              hipStream_t stream) {
    const float* x     = (const float*)d_in[0];
    const float* ea    = (const float*)d_in[1];
    const float* Wp    = (const float*)d_in[2];  // [128, 256]
    const float* W1    = (const float*)d_in[3];  // [128, 128]
    const float* b1    = (const float*)d_in[4];
    const float* pa    = (const float*)d_in[5];
    const float* gamma = (const float*)d_in[6];
    const float* beta  = (const float*)d_in[7];
    const int*   ei    = (const int*)d_in[8];
    const int*   lg    = (const int*)d_in[9];

    const int ND = 256, ED = 128;
    const int N = in_sizes[0] / ND;   // 50000
    const int E = in_sizes[1] / ED;   // 800000
    const int L = in_sizes[9] / 2;    // 1600000
    const int* src  = ei;
    const int* dstI = ei + E;
    const int* ls   = lg;
    const int* ld   = lg + L;

    float* ws = (float*)d_ws;
    size_t off = 0;
    float* px    = ws + off; off += (size_t)N * ED;
    float* fused = ws + off; off += (size_t)E * ED;
    float* aggh  = ws + off; off += (size_t)E * ED;
    float* bnsum = ws + off; off += ED;
    float* bnsq  = ws + off; off += ED;
    float* cA    = ws + off; off += ED;
    float* cB    = ws + off; off += ED;

    int* iws = (int*)(ws + off);
    size_t ioff = 0;
    int* deg_l  = iws + ioff; ioff += E;        // reused as cursor
    int* rp_l   = iws + ioff; ioff += E + 1;
    int* adj_l  = iws + ioff; ioff += L;
    int* bs_l   = iws + ioff; ioff += 1024;
    int* deg_n  = iws + ioff; ioff += N;        // reused as cursor
    int* rp_n   = iws + ioff; ioff += N + 1;
    int* adj_n  = iws + ioff; ioff += E;
    int* bs_n   = iws + ioff; ioff += 1024;

    float* out = (float*)d_out;

    const int nb_l = (E + 2047) / 2048;
    const int nb_n = (N + 2047) / 2048;

    hipMemsetAsync(bnsum, 0, 2 * ED * sizeof(float), stream);
    hipMemsetAsync(deg_l, 0, (size_t)E * sizeof(int), stream);
    hipMemsetAsync(deg_n, 0, (size_t)N * sizeof(int), stream);

    // K1: px = x @ Wp^T
    gemm_kernel<256, false><<<(N + 63) / 64, 256, 0, stream>>>(
        x, Wp, nullptr, nullptr, px, nullptr, nullptr, N);

    // K2: fused = edge_attr + 0.5*(px[src]+px[dst])
    {
        size_t tot = (size_t)E * 32;
        fuse_kernel<<<(int)((tot + 255) / 256), 256, 0, stream>>>(ea, px, src, dstI, fused, E);
    }

    // ---- line-graph CSR (bucket by destination edge ld)
    hist_kernel<<<(L + 255) / 256, 256, 0, stream>>>(ld, deg_l, L);
    scan_local_kernel<<<nb_l, 256, 0, stream>>>(deg_l, rp_l, bs_l, E);
    scan_blocks_kernel<<<1, 256, 0, stream>>>(bs_l, nb_l);
    scan_add_kernel<<<(E + 255) / 256, 256, 0, stream>>>(rp_l, bs_l, deg_l, E, L);
    fill_kernel<<<(L + 255) / 256, 256, 0, stream>>>(ld, ls, deg_l, adj_l, L);

    // ---- node CSR (bucket by dst)
    hist_kernel<<<(E + 255) / 256, 256, 0, stream>>>(dstI, deg_n, E);
    scan_local_kernel<<<nb_n, 256, 0, stream>>>(deg_n, rp_n, bs_n, N);
    scan_blocks_kernel<<<1, 256, 0, stream>>>(bs_n, nb_n);
    scan_add_kernel<<<(N + 255) / 256, 256, 0, stream>>>(rp_n, bs_n, deg_n, N, E);
    fill_kernel<<<(E + 255) / 256, 256, 0, stream>>>(dstI, nullptr, deg_n, adj_n, E);

    // K3: agg = segment-mean of fused over line graph (seg-swizzled rows)
    gather_line_kernel<<<(E + 3) / 4, 256, 0, stream>>>(fused, rp_l, adj_l, aggh, E);

    // K4: h = PReLU(agg @ W1^T + b1) + BN sums  (bf16x3 MFMA, in-place)
    gemm_h_kernel<<<256, 512, 0, stream>>>(aggh, W1, b1, pa, aggh, bnsum, bnsq, E);

    // K4b: BN coefficients
    bn_finalize_kernel<<<1, 128, 0, stream>>>(bnsum, bnsq, gamma, beta, cA, cB, 1.f / (float)E);

    // K5: out = segment-mean over dst of (fused + BN(h))  (no atomics)
    gather_node_kernel<<<(N + 3) / 4, 256, 0, stream>>>(fused, aggh, rp_n, adj_n, cA, cB, out, N);
}